// Round 2
// baseline (2035.634 us; speedup 1.0000x reference)
//
#include <hip/hip_runtime.h>

#define BB 128
#define TT 2048
#define KK 64

__device__ __forceinline__ float rlane_f(float v, int lane) {
    return __int_as_float(__builtin_amdgcn_readlane(__float_as_int(v), lane));
}

__global__ __launch_bounds__(64, 1)
void viterbi64(const float* __restrict__ em, const int* __restrict__ mask,
               const float* __restrict__ trans, int* __restrict__ out,
               unsigned char* __restrict__ bp)
{
    const int b = blockIdx.x;
    const int lane = threadIdx.x;
    const float* emb = em + (size_t)b * TT * KK;
    unsigned char* bpb = bp + (size_t)b * TT * KK;
    int* outb = out + (size_t)b * TT;

    // transition column: tcol[i] = trans[i][lane]  (64 VGPRs)
    float tcol[KK];
#pragma unroll
    for (int i = 0; i < KK; ++i) tcol[i] = trans[i * KK + lane];

    // length = index of first zero in prefix mask (or T)
    int len = TT;
#pragma unroll 1
    for (int c = 0; c < TT / 64; ++c) {
        int m = mask[b * TT + c * 64 + lane];
        unsigned long long z = __ballot(m == 0);
        if (z) { len = c * 64 + (__ffsll(z) - 1); break; }
    }
    const int lenm1 = len - 1;

    float score = emb[lane];   // t = 0 init

    // one Viterbi forward step at time tu (1 <= tu <= lenm1)
    auto step = [&](float e, int tu) {
        float c[KK];
#pragma unroll
        for (int i = 0; i < KK; ++i) c[i] = rlane_f(score, i) + tcol[i];
        // tree max (exact; order-independent)
        float m1[32];
#pragma unroll
        for (int i = 0; i < 32; ++i) m1[i] = fmaxf(c[2*i], c[2*i+1]);
        float m2[16];
#pragma unroll
        for (int i = 0; i < 16; ++i) m2[i] = fmaxf(m1[2*i], m1[2*i+1]);
        float m3[8];
#pragma unroll
        for (int i = 0; i < 8; ++i) m3[i] = fmaxf(m2[2*i], m2[2*i+1]);
        float m4[4];
#pragma unroll
        for (int i = 0; i < 4; ++i) m4[i] = fmaxf(m3[2*i], m3[2*i+1]);
        float best = fmaxf(fmaxf(m4[0], m4[1]), fmaxf(m4[2], m4[3]));
        // first-occurrence argmax: descending overwrite-on-equal
        int bpi = 0;
#pragma unroll
        for (int i = KK - 1; i >= 0; --i) bpi = (c[i] == best) ? i : bpi;
        bpb[(size_t)tu * KK + lane] = (unsigned char)bpi;
        score = best + e;
    };

    // emission prefetch buffer: ebuf[u] holds row (t+u)
    float ebuf[4];
#pragma unroll
    for (int k = 0; k < 4; ++k) {
        int tp = 1 + k; if (tp > TT - 1) tp = TT - 1;
        ebuf[k] = emb[tp * KK + lane];
    }

    int t = 1;
#pragma unroll 1
    for (; t + 3 <= lenm1; t += 4) {
#pragma unroll
        for (int u = 0; u < 4; ++u) {
            float e = ebuf[u];
            int tp = t + 4 + u; if (tp > TT - 1) tp = TT - 1;
            ebuf[u] = emb[tp * KK + lane];       // prefetch 4 ahead
            step(e, t + u);
        }
    }
#pragma unroll 1
    for (; t <= lenm1; ++t) {
        float e = emb[t * KK + lane];
        step(e, t);
    }

    // final argmax over score (first occurrence)
    float bv = score; int bi = lane;
#pragma unroll
    for (int off = 32; off; off >>= 1) {
        float ov = __shfl_xor(bv, off, 64);
        int oi = __shfl_xor(bi, off, 64);
        bool take = (ov > bv) || ((ov == bv) && (oi < bi));
        bv = take ? ov : bv;
        bi = take ? oi : bi;
    }
    int tag = __builtin_amdgcn_readfirstlane(bi);

    // make bp stores visible to our own loads
    asm volatile("s_waitcnt vmcnt(0)" ::: "memory");

    // zero-fill output rows beyond the top backtrack chunk
    const int cbase_top = lenm1 & ~63;
#pragma unroll 1
    for (int t0 = cbase_top + 64; t0 < TT; t0 += 64) outb[t0 + lane] = 0;

    // chunked backtrack: 64 bp rows live in 16 VGPRs (4x uint4)
    // reg q, lane l  <->  row cbase + 16*q + (l>>2), bytes (l&3)*16 .. +15
    const int rsub = lane >> 2;
    const int boff = (lane & 3) * 16;
    uint4 cur[4], nxt[4];
#pragma unroll
    for (int q = 0; q < 4; ++q)
        cur[q] = *(const uint4*)(bpb + (size_t)(cbase_top + 16 * q + rsub) * 64 + boff);
#pragma unroll
    for (int q = 0; q < 4; ++q) nxt[q] = cur[q];

    int stage = 0;   // per-lane staged tags for rows [cbase, cbase+63]
#pragma unroll 1
    for (int cbase = cbase_top; cbase >= 0; cbase -= 64) {
        if (cbase >= 64) {
#pragma unroll
            for (int q = 0; q < 4; ++q)
                nxt[q] = *(const uint4*)(bpb + (size_t)(cbase - 64 + 16 * q + rsub) * 64 + boff);
        }
#pragma unroll
        for (int s = 63; s >= 0; --s) {
            const int row = cbase + s;
            if (row <= lenm1) {                      // uniform branch
                stage = (lane == s) ? tag : stage;   // record tag_row
                if (row >= 1) {                      // tag_{row-1} = bp[row][tag_row]
                    const int q = s >> 4;
                    const int lanei = ((s & 15) << 2) | (tag >> 4);
                    int w0 = __builtin_amdgcn_readlane((int)cur[q].x, lanei);
                    int w1 = __builtin_amdgcn_readlane((int)cur[q].y, lanei);
                    int w2 = __builtin_amdgcn_readlane((int)cur[q].z, lanei);
                    int w3 = __builtin_amdgcn_readlane((int)cur[q].w, lanei);
                    int a0 = (tag & 4) ? w1 : w0;
                    int a1 = (tag & 4) ? w3 : w2;
                    int word = (tag & 8) ? a1 : a0;
                    tag = (word >> ((tag & 3) * 8)) & 0xFF;
                }
            }
        }
        outb[cbase + lane] = stage;
        stage = 0;
#pragma unroll
        for (int q = 0; q < 4; ++q) cur[q] = nxt[q];
    }
}

extern "C" void kernel_launch(void* const* d_in, const int* in_sizes, int n_in,
                              void* d_out, int out_size, void* d_ws, size_t ws_size,
                              hipStream_t stream)
{
    const float* em    = (const float*)d_in[0];
    const int*   mask  = (const int*)d_in[1];
    const float* trans = (const float*)d_in[2];
    int* out = (int*)d_out;
    unsigned char* bp = (unsigned char*)d_ws;   // needs B*T*K = 16 MiB
    viterbi64<<<dim3(BB), dim3(64), 0, stream>>>(em, mask, trans, out, bp);
}

// Round 3
// 1343.265 us; speedup vs baseline: 1.5154x; 1.5154x over previous
//
#include <hip/hip_runtime.h>

#define BB 128
#define TT 2048
#define KK 64

__device__ __forceinline__ float rlane_f(float v, int lane) {
    return __int_as_float(__builtin_amdgcn_readlane(__float_as_int(v), lane));
}

// pairwise argmax combine, first-occurrence on ties (a has the lower index)
__device__ __forceinline__ void cmb(float& av, int& ai, float bv, int bi) {
    bool t = bv > av;
    av = t ? bv : av;
    ai = t ? bi : ai;
}

__global__ __launch_bounds__(64, 1)
void viterbi64(const float* __restrict__ em, const int* __restrict__ mask,
               const float* __restrict__ trans, int* __restrict__ out,
               unsigned char* __restrict__ bp)
{
    const int b = blockIdx.x;
    const int lane = threadIdx.x;
    const float* emb = em + (size_t)b * TT * KK;
    unsigned char* bpb = bp + (size_t)b * TT * KK;
    int* outb = out + (size_t)b * TT;

    // transition column: tcol[i] = trans[i][lane], pinned in 64 VGPRs
    float tcol[KK];
#pragma unroll
    for (int i = 0; i < KK; ++i) tcol[i] = trans[i * KK + lane];
#pragma unroll
    for (int i = 0; i < KK; ++i) asm volatile("" : "+v"(tcol[i]));

    // length = index of first zero in prefix mask (or T)
    int len = TT;
#pragma unroll 1
    for (int c = 0; c < TT / 64; ++c) {
        int m = mask[b * TT + c * 64 + lane];
        unsigned long long z = __ballot(m == 0);
        if (z) { len = c * 64 + (__ffsll(z) - 1); break; }
    }
    const int lenm1 = len - 1;

    float score = emb[lane];   // t = 0 init

    // one Viterbi forward step at time tu (1 <= tu <= lenm1)
    // fused max+argmax tree: 8 groups of 8 sources, value+index combine
    auto step = [&](float e, int tu) {
        float gv[8]; int gi[8];
#pragma unroll
        for (int g = 0; g < 8; ++g) {
            const int base = 8 * g;
            float c0 = rlane_f(score, base + 0) + tcol[base + 0];
            float c1 = rlane_f(score, base + 1) + tcol[base + 1];
            float c2 = rlane_f(score, base + 2) + tcol[base + 2];
            float c3 = rlane_f(score, base + 3) + tcol[base + 3];
            float c4 = rlane_f(score, base + 4) + tcol[base + 4];
            float c5 = rlane_f(score, base + 5) + tcol[base + 5];
            float c6 = rlane_f(score, base + 6) + tcol[base + 6];
            float c7 = rlane_f(score, base + 7) + tcol[base + 7];
            float v0 = c0; int i0 = base + 0;
            cmb(v0, i0, c1, base + 1);
            float v1 = c2; int i1 = base + 2;
            cmb(v1, i1, c3, base + 3);
            float v2 = c4; int i2 = base + 4;
            cmb(v2, i2, c5, base + 5);
            float v3 = c6; int i3 = base + 6;
            cmb(v3, i3, c7, base + 7);
            cmb(v0, i0, v1, i1);
            cmb(v2, i2, v3, i3);
            cmb(v0, i0, v2, i2);
            gv[g] = v0; gi[g] = i0;
        }
        cmb(gv[0], gi[0], gv[1], gi[1]);
        cmb(gv[2], gi[2], gv[3], gi[3]);
        cmb(gv[4], gi[4], gv[5], gi[5]);
        cmb(gv[6], gi[6], gv[7], gi[7]);
        cmb(gv[0], gi[0], gv[2], gi[2]);
        cmb(gv[4], gi[4], gv[6], gi[6]);
        cmb(gv[0], gi[0], gv[4], gi[4]);
        bpb[(size_t)tu * KK + lane] = (unsigned char)gi[0];
        score = gv[0] + e;
    };

    // emission prefetch buffer: ebuf[u] holds row (t+u)
    float ebuf[4];
#pragma unroll
    for (int k = 0; k < 4; ++k) {
        int tp = 1 + k; if (tp > TT - 1) tp = TT - 1;
        ebuf[k] = emb[tp * KK + lane];
    }

    int t = 1;
#pragma unroll 1
    for (; t + 3 <= lenm1; t += 4) {
#pragma unroll
        for (int u = 0; u < 4; ++u) {
            float e = ebuf[u];
            int tp = t + 4 + u; if (tp > TT - 1) tp = TT - 1;
            ebuf[u] = emb[tp * KK + lane];       // prefetch 4 ahead
            step(e, t + u);
        }
    }
#pragma unroll 1
    for (; t <= lenm1; ++t) {
        float e = emb[t * KK + lane];
        step(e, t);
    }

    // final argmax over score (first occurrence)
    float bv = score; int bi = lane;
#pragma unroll
    for (int off = 32; off; off >>= 1) {
        float ov = __shfl_xor(bv, off, 64);
        int oi = __shfl_xor(bi, off, 64);
        bool take = (ov > bv) || ((ov == bv) && (oi < bi));
        bv = take ? ov : bv;
        bi = take ? oi : bi;
    }
    int tag = __builtin_amdgcn_readfirstlane(bi);

    // make bp stores visible to our own loads
    asm volatile("s_waitcnt vmcnt(0)" ::: "memory");

    // zero-fill output rows beyond the top backtrack chunk
    const int cbase_top = lenm1 & ~63;
#pragma unroll 1
    for (int t0 = cbase_top + 64; t0 < TT; t0 += 64) outb[t0 + lane] = 0;

    // chunked backtrack: 64 bp rows live in 16 VGPRs (4x uint4)
    // reg q, lane l  <->  row cbase + 16*q + (l>>2), bytes (l&3)*16 .. +15
    const int rsub = lane >> 2;
    const int boff = (lane & 3) * 16;
    uint4 cur[4], nxt[4];
#pragma unroll
    for (int q = 0; q < 4; ++q)
        cur[q] = *(const uint4*)(bpb + (size_t)(cbase_top + 16 * q + rsub) * 64 + boff);
#pragma unroll
    for (int q = 0; q < 4; ++q) nxt[q] = cur[q];

    int stage = 0;   // per-lane staged tags for rows [cbase, cbase+63]
#pragma unroll 1
    for (int cbase = cbase_top; cbase >= 0; cbase -= 64) {
        if (cbase >= 64) {
#pragma unroll
            for (int q = 0; q < 4; ++q)
                nxt[q] = *(const uint4*)(bpb + (size_t)(cbase - 64 + 16 * q + rsub) * 64 + boff);
        }
#pragma unroll
        for (int s = 63; s >= 0; --s) {
            const int row = cbase + s;
            if (row <= lenm1) {                      // uniform branch
                stage = (lane == s) ? tag : stage;   // record tag_row
                if (row >= 1) {                      // tag_{row-1} = bp[row][tag_row]
                    const int q = s >> 4;
                    const int lanei = ((s & 15) << 2) | (tag >> 4);
                    int w0 = __builtin_amdgcn_readlane((int)cur[q].x, lanei);
                    int w1 = __builtin_amdgcn_readlane((int)cur[q].y, lanei);
                    int w2 = __builtin_amdgcn_readlane((int)cur[q].z, lanei);
                    int w3 = __builtin_amdgcn_readlane((int)cur[q].w, lanei);
                    int a0 = (tag & 4) ? w1 : w0;
                    int a1 = (tag & 4) ? w3 : w2;
                    int word = (tag & 8) ? a1 : a0;
                    tag = (word >> ((tag & 3) * 8)) & 0xFF;
                }
            }
        }
        outb[cbase + lane] = stage;
        stage = 0;
#pragma unroll
        for (int q = 0; q < 4; ++q) cur[q] = nxt[q];
    }
}

extern "C" void kernel_launch(void* const* d_in, const int* in_sizes, int n_in,
                              void* d_out, int out_size, void* d_ws, size_t ws_size,
                              hipStream_t stream)
{
    const float* em    = (const float*)d_in[0];
    const int*   mask  = (const int*)d_in[1];
    const float* trans = (const float*)d_in[2];
    int* out = (int*)d_out;
    unsigned char* bp = (unsigned char*)d_ws;   // needs B*T*K = 16 MiB
    viterbi64<<<dim3(BB), dim3(64), 0, stream>>>(em, mask, trans, out, bp);
}

// Round 5
// 1203.027 us; speedup vs baseline: 1.6921x; 1.1166x over previous
//
#include <hip/hip_runtime.h>

#define BB 128
#define TT 2048
#define KK 64

// 3-way argmax combine, first-occurrence on ties (requires ai<bi<ci ranges)
__device__ __forceinline__ void cmb3(float av, int ai, float bv, int bi,
                                     float cv, int ci, float& ov, int& oi) {
    float m = fmaxf(fmaxf(av, bv), cv);   // folds to v_max3_f32
    int tbc = (bv == m) ? bi : ci;
    oi = (av == m) ? ai : tbc;
    ov = m;
}

__global__ __launch_bounds__(64) __attribute__((amdgpu_waves_per_eu(1, 1)))
void viterbi64(const float* __restrict__ em, const int* __restrict__ mask,
               const float* __restrict__ trans, int* __restrict__ out,
               unsigned char* __restrict__ bp)
{
    __shared__ __align__(16) float sv[KK];   // score vector, wave-synchronous
    const int b = blockIdx.x;
    const int lane = threadIdx.x;
    const float* emb = em + (size_t)b * TT * KK;
    unsigned char* bpb = bp + (size_t)b * TT * KK;
    int* outb = out + (size_t)b * TT;

    // transition column: tcol[i] = trans[i][lane], pinned resident
    float tcol[KK];
#pragma unroll
    for (int i = 0; i < KK; ++i) tcol[i] = trans[i * KK + lane];
#pragma unroll
    for (int i = 0; i < KK; ++i) asm volatile("" : "+v"(tcol[i]));

    // length = index of first zero in prefix mask (or T)
    int len = TT;
#pragma unroll 1
    for (int c = 0; c < TT / 64; ++c) {
        int m = mask[b * TT + c * 64 + lane];
        unsigned long long z = __ballot(m == 0);
        if (z) { len = c * 64 + (__ffsll(z) - 1); break; }
    }
    const int lenm1 = len - 1;

    float score = emb[lane];   // t = 0 init
    sv[lane] = score;

    // one Viterbi forward step at time tu (1 <= tu <= lenm1)
    auto step = [&](float e, int tu) {
        // cand[i] = score_vec[i] + tcol[i]; score_vec broadcast from LDS
        const float4* svq = (const float4*)sv;
        float c[KK];
#pragma unroll
        for (int g = 0; g < 16; ++g) {
            float4 s = svq[g];
            c[4*g+0] = s.x + tcol[4*g+0];
            c[4*g+1] = s.y + tcol[4*g+1];
            c[4*g+2] = s.z + tcol[4*g+2];
            c[4*g+3] = s.w + tcol[4*g+3];
        }
        // fused max+argmax via 3-way tree (v_max3), first-occurrence ties
        float v1[22]; int i1[22];
#pragma unroll
        for (int g = 0; g < 21; ++g)
            cmb3(c[3*g], 3*g, c[3*g+1], 3*g+1, c[3*g+2], 3*g+2, v1[g], i1[g]);
        v1[21] = c[63]; i1[21] = 63;
        float v2[8]; int i2[8];
#pragma unroll
        for (int g = 0; g < 7; ++g)
            cmb3(v1[3*g], i1[3*g], v1[3*g+1], i1[3*g+1], v1[3*g+2], i1[3*g+2],
                 v2[g], i2[g]);
        v2[7] = v1[21]; i2[7] = i1[21];
        float v3[4]; int i3[4];
        cmb3(v2[0], i2[0], v2[1], i2[1], v2[2], i2[2], v3[0], i3[0]);
        cmb3(v2[3], i2[3], v2[4], i2[4], v2[5], i2[5], v3[1], i3[1]);
        v3[2] = v2[6]; i3[2] = i2[6];
        v3[3] = v2[7]; i3[3] = i2[7];
        float v4; int i4;
        cmb3(v3[0], i3[0], v3[1], i3[1], v3[2], i3[2], v4, i4);
        bool tk = v3[3] > v4;                 // 2-way, left wins ties
        float best = tk ? v3[3] : v4;
        int bpi = tk ? i3[3] : i4;

        bpb[(size_t)tu * KK + lane] = (unsigned char)bpi;
        score = best + e;
        sv[lane] = score;                     // publish for next step
    };

    // emission prefetch buffer: ebuf[u] holds row (t+u)
    float ebuf[4];
#pragma unroll
    for (int k = 0; k < 4; ++k) {
        int tp = 1 + k; if (tp > TT - 1) tp = TT - 1;
        ebuf[k] = emb[tp * KK + lane];
    }

    int t = 1;
#pragma unroll 1
    for (; t + 3 <= lenm1; t += 4) {
#pragma unroll
        for (int u = 0; u < 4; ++u) {
            float e = ebuf[u];
            int tp = t + 4 + u; if (tp > TT - 1) tp = TT - 1;
            ebuf[u] = emb[tp * KK + lane];       // prefetch 4 ahead
            step(e, t + u);
        }
    }
#pragma unroll 1
    for (; t <= lenm1; ++t) {
        float e = emb[t * KK + lane];
        step(e, t);
    }

    // final argmax over score (first occurrence)
    float bv = score; int bi = lane;
#pragma unroll
    for (int off = 32; off; off >>= 1) {
        float ov = __shfl_xor(bv, off, 64);
        int oi = __shfl_xor(bi, off, 64);
        bool take = (ov > bv) || ((ov == bv) && (oi < bi));
        bv = take ? ov : bv;
        bi = take ? oi : bi;
    }
    int tag = __builtin_amdgcn_readfirstlane(bi);

    // make bp stores visible to our own loads
    asm volatile("s_waitcnt vmcnt(0)" ::: "memory");

    // zero-fill output rows beyond the top backtrack chunk
    const int cbase_top = lenm1 & ~63;
#pragma unroll 1
    for (int t0 = cbase_top + 64; t0 < TT; t0 += 64) outb[t0 + lane] = 0;

    // chunked backtrack: 64 bp rows live in 16 VGPRs (4x uint4)
    // reg q, lane l  <->  row cbase + 16*q + (l>>2), bytes (l&3)*16 .. +15
    const int rsub = lane >> 2;
    const int boff = (lane & 3) * 16;
    uint4 cur[4], nxt[4];
#pragma unroll
    for (int q = 0; q < 4; ++q)
        cur[q] = *(const uint4*)(bpb + (size_t)(cbase_top + 16 * q + rsub) * 64 + boff);
#pragma unroll
    for (int q = 0; q < 4; ++q) nxt[q] = cur[q];

    int stage = 0;   // per-lane staged tags for rows [cbase, cbase+63]
#pragma unroll 1
    for (int cbase = cbase_top; cbase >= 0; cbase -= 64) {
        if (cbase >= 64) {
#pragma unroll
            for (int q = 0; q < 4; ++q)
                nxt[q] = *(const uint4*)(bpb + (size_t)(cbase - 64 + 16 * q + rsub) * 64 + boff);
        }
#pragma unroll
        for (int s = 63; s >= 0; --s) {
            const int row = cbase + s;
            if (row <= lenm1) {                      // uniform branch
                stage = (lane == s) ? tag : stage;   // record tag_row
                if (row >= 1) {                      // tag_{row-1} = bp[row][tag_row]
                    const int q = s >> 4;
                    const int lanei = ((s & 15) << 2) | (tag >> 4);
                    int w0 = __builtin_amdgcn_readlane((int)cur[q].x, lanei);
                    int w1 = __builtin_amdgcn_readlane((int)cur[q].y, lanei);
                    int w2 = __builtin_amdgcn_readlane((int)cur[q].z, lanei);
                    int w3 = __builtin_amdgcn_readlane((int)cur[q].w, lanei);
                    int a0 = (tag & 4) ? w1 : w0;
                    int a1 = (tag & 4) ? w3 : w2;
                    int word = (tag & 8) ? a1 : a0;
                    tag = (word >> ((tag & 3) * 8)) & 0xFF;
                }
            }
        }
        outb[cbase + lane] = stage;
        stage = 0;
#pragma unroll
        for (int q = 0; q < 4; ++q) cur[q] = nxt[q];
    }
}

extern "C" void kernel_launch(void* const* d_in, const int* in_sizes, int n_in,
                              void* d_out, int out_size, void* d_ws, size_t ws_size,
                              hipStream_t stream)
{
    const float* em    = (const float*)d_in[0];
    const int*   mask  = (const int*)d_in[1];
    const float* trans = (const float*)d_in[2];
    int* out = (int*)d_out;
    unsigned char* bp = (unsigned char*)d_ws;   // needs B*T*K = 16 MiB
    viterbi64<<<dim3(BB), dim3(64), 0, stream>>>(em, mask, trans, out, bp);
}